// Round 1
// baseline (173.506 us; speedup 1.0000x reference)
//
#include <hip/hip_runtime.h>

// Problem constants (B,C,W,H,D = 4,32,64,64,64)
#define MSP   262144          // 64*64*64 spatial per (b, ch)
#define TILE  256             // positions per LDS tile
#define TPB   8               // tiles per block
#define NBLK  128             // MSP / (TILE*TPB)
#define BATCH 4

// ws layout (float offsets)
#define OFF_UT   0            // U^T packed: Ut[bb*32+aa] = U[aa][bb], 1024
#define OFF_U    1024         // u[a] = sum_ch Wq[ch,a]*bk[ch], 32
#define OFF_V    1056         // v[b] = sum_ch bq[ch]*Wk[ch,b], 32
#define OFF_BETA 1088         // sum_ch bq*bk, 1
#define OFF_P    1152         // P[b][i][j], 4*1024
#define OFF_CS   5248         // colsum[b][a][i], 4*1024
#define OFF_A    9344         // softmax A[b][i][j], 4*1024

__global__ __launch_bounds__(1024) void prep_kernel(
    const float* __restrict__ Wq, const float* __restrict__ bq,
    const float* __restrict__ Wk, const float* __restrict__ bk,
    float* __restrict__ ws) {
  const int tid = threadIdx.x;
  const int aa = tid & 31, bb = tid >> 5;
  float s = 0.f;
  for (int ch = 0; ch < 32; ++ch)
    s = fmaf(Wq[ch * 32 + aa], Wk[ch * 32 + bb], s);
  ws[OFF_UT + bb * 32 + aa] = s;   // U[aa][bb]
  if (tid < 32) {
    float u = 0.f, v = 0.f;
    for (int ch = 0; ch < 32; ++ch) {
      u = fmaf(Wq[ch * 32 + tid], bk[ch], u);
      v = fmaf(bq[ch], Wk[ch * 32 + tid], v);
    }
    ws[OFF_U + tid] = u;
    ws[OFF_V + tid] = v;
  }
  if (tid == 0) {
    float bt = 0.f;
    for (int ch = 0; ch < 32; ++ch) bt = fmaf(bq[ch], bk[ch], bt);
    ws[OFF_BETA] = bt;
  }
  // zero P and colsum accumulators (they are atomicAdd targets each launch)
  for (int k = tid; k < 8192; k += 1024) ws[OFF_P + k] = 0.f;
}

// Pass 1: P[b][i][j] += sum over groups of X_g^T (U X_g); colsum[b][a][i]
__global__ __launch_bounds__(256) void pass1_kernel(
    const float* __restrict__ x, float* __restrict__ ws) {
  __shared__ float XT[32][256];
  __shared__ float YT[32][256];
  __shared__ float Ulds[1024];

  const int tid = threadIdx.x;
  const int b = blockIdx.y;
  const size_t base = (size_t)b * 32 * MSP;
  const int m0_blk = blockIdx.x * (TILE * TPB);

  for (int k = tid; k < 1024; k += 256) Ulds[k] = ws[OFF_UT + k];

  float acc[32];
#pragma unroll
  for (int j = 0; j < 32; ++j) acc[j] = 0.f;
  float csum[4] = {0.f, 0.f, 0.f, 0.f};

  const int i_p = tid & 31, w_p = tid >> 5;          // P-accum role
  const int wp32 = w_p * 32;
  const int a_c = tid >> 3, i0_c = (tid & 7) * 4;    // colsum role
  const int aag4 = (tid >> 5) * 4, colg4 = (tid & 31) * 4;  // Y-proj role

  __syncthreads();

#pragma unroll 1
  for (int t = 0; t < TPB; ++t) {
    const int m0 = m0_blk + t * TILE;

    // phase 1: global -> LDS (coalesced float4)
    {
      const int col4 = (tid & 63) * 4;
      const int arow = tid >> 6;
#pragma unroll
      for (int rep = 0; rep < 8; ++rep) {
        const int a = rep * 4 + arow;
        const float4 v = *reinterpret_cast<const float4*>(
            &x[base + (size_t)a * MSP + m0 + col4]);
        *reinterpret_cast<float4*>(&XT[a][col4]) = v;
      }
    }
    __syncthreads();

    // phase 2: colsum partials (thread owns unique (a, i0..i0+3))
#pragma unroll
    for (int k = 0; k < 4; ++k) {
      float s = 0.f;
#pragma unroll
      for (int g = 0; g < 8; ++g) s += XT[a_c][g * 32 + i0_c + k];
      csum[k] += s;
    }

    // phase 3: Y = U * X  (4 rows x 8 cols per thread)
    {
      float y[4][8];
#pragma unroll
      for (int r = 0; r < 4; ++r)
#pragma unroll
        for (int c = 0; c < 8; ++c) y[r][c] = 0.f;
#pragma unroll 4
      for (int bb = 0; bb < 32; ++bb) {
        const float4 u4 = *reinterpret_cast<const float4*>(&Ulds[bb * 32 + aag4]);
        const float4 xl = *reinterpret_cast<const float4*>(&XT[bb][colg4]);
        const float4 xh = *reinterpret_cast<const float4*>(&XT[bb][128 + colg4]);
        const float uu[4] = {u4.x, u4.y, u4.z, u4.w};
        const float xx[8] = {xl.x, xl.y, xl.z, xl.w, xh.x, xh.y, xh.z, xh.w};
#pragma unroll
        for (int r = 0; r < 4; ++r)
#pragma unroll
          for (int c = 0; c < 8; ++c) y[r][c] = fmaf(uu[r], xx[c], y[r][c]);
      }
#pragma unroll
      for (int r = 0; r < 4; ++r) {
        *reinterpret_cast<float4*>(&YT[aag4 + r][colg4]) =
            make_float4(y[r][0], y[r][1], y[r][2], y[r][3]);
        *reinterpret_cast<float4*>(&YT[aag4 + r][128 + colg4]) =
            make_float4(y[r][4], y[r][5], y[r][6], y[r][7]);
      }
    }
    __syncthreads();

    // phase 4: P accumulation. thread (i_p, w_p): acc[j] += sum_a X[a][32w+i]*Y[a][32w+j]
#pragma unroll 2
    for (int a = 0; a < 32; a += 4) {
      float xa[4];
#pragma unroll
      for (int aa = 0; aa < 4; ++aa) xa[aa] = XT[a + aa][wp32 + i_p];
#pragma unroll
      for (int jj = 0; jj < 8; ++jj) {
#pragma unroll
        for (int aa = 0; aa < 4; ++aa) {
          const float4 y4 =
              *reinterpret_cast<const float4*>(&YT[a + aa][wp32 + jj * 4]);
          acc[jj * 4 + 0] = fmaf(xa[aa], y4.x, acc[jj * 4 + 0]);
          acc[jj * 4 + 1] = fmaf(xa[aa], y4.y, acc[jj * 4 + 1]);
          acc[jj * 4 + 2] = fmaf(xa[aa], y4.z, acc[jj * 4 + 2]);
          acc[jj * 4 + 3] = fmaf(xa[aa], y4.w, acc[jj * 4 + 3]);
        }
      }
    }
    __syncthreads();
  }

  // block-level reduce of the 8 w-partials, then one atomicAdd per (i,j)
  {
    float(*PL)[32][32] = (float(*)[32][32]) & XT[0][0];
#pragma unroll
    for (int jq = 0; jq < 8; ++jq)
      *reinterpret_cast<float4*>(&PL[w_p][i_p][jq * 4]) = make_float4(
          acc[jq * 4], acc[jq * 4 + 1], acc[jq * 4 + 2], acc[jq * 4 + 3]);
    __syncthreads();
    const int iq = tid >> 3, j0 = (tid & 7) * 4;
    float4 sum = *reinterpret_cast<const float4*>(&PL[0][iq][j0]);
#pragma unroll
    for (int w = 1; w < 8; ++w) {
      const float4 p = *reinterpret_cast<const float4*>(&PL[w][iq][j0]);
      sum.x += p.x; sum.y += p.y; sum.z += p.z; sum.w += p.w;
    }
    float* Pg = ws + OFF_P + ((size_t)b * 32 + iq) * 32 + j0;
    atomicAdd(Pg + 0, sum.x);
    atomicAdd(Pg + 1, sum.y);
    atomicAdd(Pg + 2, sum.z);
    atomicAdd(Pg + 3, sum.w);
#pragma unroll
    for (int k = 0; k < 4; ++k)
      atomicAdd(&ws[OFF_CS + ((size_t)b * 32 + a_c) * 32 + i0_c + k], csum[k]);
  }
}

// s[b,i,j] = P + u.colsum_i + v.colsum_j + 8192*beta; A = softmax_j(s)
__global__ __launch_bounds__(1024) void softmax_kernel(float* __restrict__ ws) {
  const int j = threadIdx.x, i = threadIdx.y, b = blockIdx.x;
  const float* P = ws + OFF_P;
  const float* cs = ws + OFF_CS;
  float s = P[((size_t)b * 32 + i) * 32 + j] + 8192.0f * ws[OFF_BETA];
  for (int a = 0; a < 32; ++a) {
    s = fmaf(ws[OFF_U + a], cs[((size_t)b * 32 + a) * 32 + i], s);
    s = fmaf(ws[OFF_V + a], cs[((size_t)b * 32 + a) * 32 + j], s);
  }
  float mx = s;
#pragma unroll
  for (int off = 16; off > 0; off >>= 1)
    mx = fmaxf(mx, __shfl_xor(mx, off, 32));
  const float e = expf(s - mx);
  float sum = e;
#pragma unroll
  for (int off = 16; off > 0; off >>= 1) sum += __shfl_xor(sum, off, 32);
  ws[OFF_A + ((size_t)b * 32 + i) * 32 + j] = e / sum;
}

// Pass 2: out = x + gamma * (per-group V_g * A), V = Wv*X + bv
__global__ __launch_bounds__(256) void pass2_kernel(
    const float* __restrict__ x, const float* __restrict__ Wv,
    const float* __restrict__ bv, const float* __restrict__ gamma_p,
    const float* __restrict__ ws, float* __restrict__ out) {
  __shared__ float XT[32][256];
  __shared__ float VT[32][256];
  __shared__ float Wvt[32][32];  // [cin][ch]
  __shared__ float Alds[32][32];
  __shared__ float bvl[32];

  const int tid = threadIdx.x;
  const int b = blockIdx.y;
  const float gamma = gamma_p[0];

  for (int k = tid; k < 1024; k += 256) {
    const int ch = k >> 5, cin = k & 31;
    Wvt[cin][ch] = Wv[k];  // Wv[ch*32+cin]
    Alds[ch][cin] = ws[OFF_A + ((size_t)b * 32 + ch) * 32 + cin];  // Alds[i][j]
  }
  if (tid < 32) bvl[tid] = bv[tid];
  __syncthreads();

  const int ch0 = (tid >> 5) * 4, colg = tid & 31;
  const int colg4 = colg * 4;
  const int g1 = colg >> 3, g2 = 4 + (colg >> 3);
  const int ja = (colg & 7) * 4;
  const size_t base = (size_t)b * 32 * MSP;
  const int m0_blk = blockIdx.x * (TILE * TPB);

#pragma unroll 1
  for (int t = 0; t < TPB; ++t) {
    const int m0 = m0_blk + t * TILE;

    // load XT
    {
      const int col4 = (tid & 63) * 4;
      const int arow = tid >> 6;
#pragma unroll
      for (int rep = 0; rep < 8; ++rep) {
        const int a = rep * 4 + arow;
        const float4 v = *reinterpret_cast<const float4*>(
            &x[base + (size_t)a * MSP + m0 + col4]);
        *reinterpret_cast<float4*>(&XT[a][col4]) = v;
      }
    }
    __syncthreads();

    // V = Wv*X + bv (4 rows x 8 cols per thread)
    {
      float y[4][8];
#pragma unroll
      for (int r = 0; r < 4; ++r)
#pragma unroll
        for (int c = 0; c < 8; ++c) y[r][c] = bvl[ch0 + r];
#pragma unroll 4
      for (int cin = 0; cin < 32; ++cin) {
        const float4 u4 = *reinterpret_cast<const float4*>(&Wvt[cin][ch0]);
        const float4 xl = *reinterpret_cast<const float4*>(&XT[cin][colg4]);
        const float4 xh = *reinterpret_cast<const float4*>(&XT[cin][128 + colg4]);
        const float uu[4] = {u4.x, u4.y, u4.z, u4.w};
        const float xx[8] = {xl.x, xl.y, xl.z, xl.w, xh.x, xh.y, xh.z, xh.w};
#pragma unroll
        for (int r = 0; r < 4; ++r)
#pragma unroll
          for (int c = 0; c < 8; ++c) y[r][c] = fmaf(uu[r], xx[c], y[r][c]);
      }
#pragma unroll
      for (int r = 0; r < 4; ++r) {
        *reinterpret_cast<float4*>(&VT[ch0 + r][colg4]) =
            make_float4(y[r][0], y[r][1], y[r][2], y[r][3]);
        *reinterpret_cast<float4*>(&VT[ch0 + r][128 + colg4]) =
            make_float4(y[r][4], y[r][5], y[r][6], y[r][7]);
      }
    }
    __syncthreads();

    // scores + residual + store
    {
      float accl[4][4], acch[4][4];
#pragma unroll
      for (int r = 0; r < 4; ++r)
#pragma unroll
        for (int c = 0; c < 4; ++c) { accl[r][c] = 0.f; acch[r][c] = 0.f; }

#pragma unroll 2
      for (int i4 = 0; i4 < 8; ++i4) {
        float av[4][4];
#pragma unroll
        for (int s = 0; s < 4; ++s) {
          const float4 a4 = *reinterpret_cast<const float4*>(&Alds[i4 * 4 + s][ja]);
          av[s][0] = a4.x; av[s][1] = a4.y; av[s][2] = a4.z; av[s][3] = a4.w;
        }
#pragma unroll
        for (int r = 0; r < 4; ++r) {
          const float4 vl4 = *reinterpret_cast<const float4*>(&VT[ch0 + r][g1 * 32 + i4 * 4]);
          const float4 vh4 = *reinterpret_cast<const float4*>(&VT[ch0 + r][g2 * 32 + i4 * 4]);
          const float vl[4] = {vl4.x, vl4.y, vl4.z, vl4.w};
          const float vh[4] = {vh4.x, vh4.y, vh4.z, vh4.w};
#pragma unroll
          for (int s = 0; s < 4; ++s)
#pragma unroll
            for (int c = 0; c < 4; ++c) {
              accl[r][c] = fmaf(vl[s], av[s][c], accl[r][c]);
              acch[r][c] = fmaf(vh[s], av[s][c], acch[r][c]);
            }
        }
      }

#pragma unroll
      for (int r = 0; r < 4; ++r) {
        const float4 xl = *reinterpret_cast<const float4*>(&XT[ch0 + r][colg4]);
        const float4 xh = *reinterpret_cast<const float4*>(&XT[ch0 + r][128 + colg4]);
        const float4 olo = make_float4(fmaf(gamma, accl[r][0], xl.x),
                                       fmaf(gamma, accl[r][1], xl.y),
                                       fmaf(gamma, accl[r][2], xl.z),
                                       fmaf(gamma, accl[r][3], xl.w));
        const float4 ohi = make_float4(fmaf(gamma, acch[r][0], xh.x),
                                       fmaf(gamma, acch[r][1], xh.y),
                                       fmaf(gamma, acch[r][2], xh.z),
                                       fmaf(gamma, acch[r][3], xh.w));
        *reinterpret_cast<float4*>(&out[base + (size_t)(ch0 + r) * MSP + m0 + colg4]) = olo;
        *reinterpret_cast<float4*>(&out[base + (size_t)(ch0 + r) * MSP + m0 + 128 + colg4]) = ohi;
      }
    }
    __syncthreads();
  }
}

extern "C" void kernel_launch(void* const* d_in, const int* in_sizes, int n_in,
                              void* d_out, int out_size, void* d_ws, size_t ws_size,
                              hipStream_t stream) {
  const float* x  = (const float*)d_in[0];
  const float* Wq = (const float*)d_in[1];
  const float* bq = (const float*)d_in[2];
  const float* Wk = (const float*)d_in[3];
  const float* bk = (const float*)d_in[4];
  const float* Wv = (const float*)d_in[5];
  const float* bv = (const float*)d_in[6];
  const float* gm = (const float*)d_in[7];
  float* out = (float*)d_out;
  float* ws  = (float*)d_ws;

  prep_kernel<<<1, 1024, 0, stream>>>(Wq, bq, Wk, bk, ws);
  pass1_kernel<<<dim3(NBLK, BATCH), 256, 0, stream>>>(x, ws);
  softmax_kernel<<<BATCH, dim3(32, 32), 0, stream>>>(ws);
  pass2_kernel<<<dim3(NBLK, BATCH), 256, 0, stream>>>(x, Wv, bv, gm, ws, out);
}

// Round 2
// 129.556 us; speedup vs baseline: 1.3392x; 1.3392x over previous
//
#include <hip/hip_runtime.h>

typedef __attribute__((ext_vector_type(8))) short bf16x8;
typedef __attribute__((ext_vector_type(4))) float f32x4;

#define MSP   262144          // 64*64*64 spatial per (b, ch)
#define BATCH 4
#define NGRP  8192            // groups of 32 positions per batch
#define GPW   8               // groups per wave
#define WPB   4               // waves per block (256 threads)
#define GPB   (GPW * WPB)     // 32 groups per block
#define NBLK  (NGRP / GPB)    // 256 blocks per batch

// ws layout (float offsets)
#define OFF_U      0          // u[32]
#define OFF_V      32         // v[32]
#define OFF_BETA   64         // 1
#define OFF_CA     96         // ca[4][32] (column sums of A)
#define OFF_P      256        // P[4][32][32]
#define OFF_CS     4352       // colsum[4][32][32]
#define OFF_UFRAG  8448       // U frags [ct][split][64 lanes] x 16B = 1024 floats
#define OFF_WVFRAG 9472       // Wv frags [ct][64] x 16B = 512 floats
#define OFF_AFRAG  9984       // A frags [b][mt][64] x 16B = 2048 floats

__device__ __forceinline__ unsigned short f2bf(float f) {
  unsigned int u = __float_as_uint(f);
  u += 0x7fffu + ((u >> 16) & 1u);        // round-to-nearest-even
  return (unsigned short)(u >> 16);
}
__device__ __forceinline__ float bf2f(unsigned short h) {
  return __uint_as_float(((unsigned int)h) << 16);
}

#define MFMA(A, B, C) __builtin_amdgcn_mfma_f32_16x16x32_bf16(A, B, C, 0, 0, 0)

// k-hat mapping: reg r<4 -> ch = 4*lb+r (from chtile0 acc), r>=4 -> 16+4*lb+(r-4) (chtile1)
// Used consistently for BOTH operands of every MFMA => any true HW k-order cancels.

__global__ __launch_bounds__(1024) void prep_kernel(
    const float* __restrict__ Wq, const float* __restrict__ bq,
    const float* __restrict__ Wk, const float* __restrict__ bk,
    const float* __restrict__ Wv, float* __restrict__ ws) {
  __shared__ float Ulds[32][32];
  const int tid = threadIdx.x;
  const int aa = tid & 31, bb = tid >> 5;
  float s = 0.f;
  for (int ch = 0; ch < 32; ++ch) s = fmaf(Wq[ch * 32 + aa], Wk[ch * 32 + bb], s);
  Ulds[aa][bb] = s;   // U[aa][bb] = sum_o Wq[o][aa] * Wk[o][bb]
  if (tid < 32) {
    float u = 0.f, v = 0.f;
    for (int ch = 0; ch < 32; ++ch) {
      u = fmaf(Wq[ch * 32 + tid], bk[ch], u);
      v = fmaf(bq[ch], Wk[ch * 32 + tid], v);
    }
    ws[OFF_U + tid] = u;
    ws[OFF_V + tid] = v;
  }
  if (tid == 0) {
    float bt = 0.f;
    for (int ch = 0; ch < 32; ++ch) bt = fmaf(bq[ch], bk[ch], bt);
    ws[OFF_BETA] = bt;
  }
  // zero atomic accumulators P and colsum (fresh every call)
  for (int k = tid; k < 8192; k += 1024) ws[OFF_P + k] = 0.f;
  __syncthreads();
  if (tid < 64) {
    const int lm = tid & 15, lb = tid >> 4;
    unsigned short* ufr = (unsigned short*)(ws + OFF_UFRAG);
    unsigned short* wfr = (unsigned short*)(ws + OFF_WVFRAG);
#pragma unroll
    for (int ct = 0; ct < 2; ++ct) {
#pragma unroll
      for (int r = 0; r < 8; ++r) {
        const int kk = (r < 4) ? lb * 4 + r : 16 + lb * 4 + (r - 4);
        const float uval = Ulds[ct * 16 + lm][kk];       // A-frag: U[m=ct*16+lm][k]
        const unsigned short h = f2bf(uval);
        ufr[((ct * 2 + 0) * 64 + tid) * 8 + r] = h;
        ufr[((ct * 2 + 1) * 64 + tid) * 8 + r] = f2bf(uval - bf2f(h));
        // pass2 chmix B-frag: B[k=cin][n=ch] = Wv[ch][cin]
        wfr[(ct * 64 + tid) * 8 + r] = f2bf(Wv[(ct * 16 + lm) * 32 + kk]);
      }
    }
  }
}

// Pass 1: Y = U*X (MFMA), P += X_g^T Y_g (MFMA), colsum from fp32 loads.
__global__ __launch_bounds__(256) void pass1_kernel(const float* __restrict__ x,
                                                    float* __restrict__ ws) {
  const int tid = threadIdx.x;
  const int w = tid >> 6;
  const int l = tid & 63;
  const int lm = tid & 15;
  const int lb = (tid >> 4) & 3;
  const int b = blockIdx.y;
  const size_t xbase = (size_t)b * 32 * MSP;

  const bf16x8* UF = (const bf16x8*)(ws + OFF_UFRAG);
  const bf16x8 uh0 = UF[0 * 64 + l];  // chtile0 hi
  const bf16x8 ul0 = UF[1 * 64 + l];  // chtile0 lo
  const bf16x8 uh1 = UF[2 * 64 + l];  // chtile1 hi
  const bf16x8 ul1 = UF[3 * 64 + l];  // chtile1 lo

  const float* rowp[8];
#pragma unroll
  for (int r = 0; r < 8; ++r) {
    const int ch = (r < 4) ? lb * 4 + r : 16 + lb * 4 + (r - 4);
    rowp[r] = x + xbase + (size_t)ch * MSP + lm;
  }

  f32x4 p00 = {0, 0, 0, 0}, p01 = {0, 0, 0, 0}, p10 = {0, 0, 0, 0}, p11 = {0, 0, 0, 0};
  float cs0[8], cs1[8];
#pragma unroll
  for (int r = 0; r < 8; ++r) { cs0[r] = 0.f; cs1[r] = 0.f; }

  const int g0 = blockIdx.x * GPB + w * GPW;
#pragma unroll 2
  for (int t = 0; t < GPW; ++t) {
    const int p0 = (g0 + t) * 32;
    float xf0[8], xf1[8];
#pragma unroll
    for (int r = 0; r < 8; ++r) { xf0[r] = rowp[r][p0]; xf1[r] = rowp[r][p0 + 16]; }

    bf16x8 xh0, xl0, xh1, xl1;
#pragma unroll
    for (int r = 0; r < 8; ++r) {
      const unsigned short h0 = f2bf(xf0[r]);
      xh0[r] = (short)h0; xl0[r] = (short)f2bf(xf0[r] - bf2f(h0));
      const unsigned short h1 = f2bf(xf1[r]);
      xh1[r] = (short)h1; xl1[r] = (short)f2bf(xf1[r] - bf2f(h1));
      cs0[r] += xf0[r];  cs1[r] += xf1[r];
    }

    // channel mix: Y[ch][pos], A=U (m=ch), B=X (n=pos); split: hh + hl + lh
    f32x4 y00 = {0,0,0,0}, y01 = {0,0,0,0}, y10 = {0,0,0,0}, y11 = {0,0,0,0};
    y00 = MFMA(uh0, xh0, y00); y00 = MFMA(uh0, xl0, y00); y00 = MFMA(ul0, xh0, y00);
    y01 = MFMA(uh1, xh0, y01); y01 = MFMA(uh1, xl0, y01); y01 = MFMA(ul1, xh0, y01);
    y10 = MFMA(uh0, xh1, y10); y10 = MFMA(uh0, xl1, y10); y10 = MFMA(ul0, xh1, y10);
    y11 = MFMA(uh1, xh1, y11); y11 = MFMA(uh1, xl1, y11); y11 = MFMA(ul1, xh1, y11);

    // repack Y accs (row=ch=lb*4+reg, col=pos=lm) into k-hat B-frags + split
    bf16x8 yh0, yl0, yh1, yl1;
#pragma unroll
    for (int r = 0; r < 4; ++r) {
      const float v0 = y00[r];
      unsigned short h = f2bf(v0); yh0[r] = (short)h; yl0[r] = (short)f2bf(v0 - bf2f(h));
      const float v1 = y10[r];
      h = f2bf(v1); yh1[r] = (short)h; yl1[r] = (short)f2bf(v1 - bf2f(h));
    }
#pragma unroll
    for (int r = 4; r < 8; ++r) {
      const float v0 = y01[r - 4];
      unsigned short h = f2bf(v0); yh0[r] = (short)h; yl0[r] = (short)f2bf(v0 - bf2f(h));
      const float v1 = y11[r - 4];
      h = f2bf(v1); yh1[r] = (short)h; yl1[r] = (short)f2bf(v1 - bf2f(h));
    }

    // Gram: P[itile][jtile] += X_chunk(itile)^T * Y_chunk(jtile); hh + hl + lh
    p00 = MFMA(xh0, yh0, p00); p00 = MFMA(xh0, yl0, p00); p00 = MFMA(xl0, yh0, p00);
    p01 = MFMA(xh0, yh1, p01); p01 = MFMA(xh0, yl1, p01); p01 = MFMA(xl0, yh1, p01);
    p10 = MFMA(xh1, yh0, p10); p10 = MFMA(xh1, yl0, p10); p10 = MFMA(xl1, yh0, p10);
    p11 = MFMA(xh1, yh1, p11); p11 = MFMA(xh1, yl1, p11); p11 = MFMA(xl1, yh1, p11);
  }

  // block reduce P (row i = itile*16 + lb*4 + reg, col j = jtile*16 + lm)
  __shared__ float red[WPB][1024];
#pragma unroll
  for (int r = 0; r < 4; ++r) {
    red[w][(lb * 4 + r) * 32 + lm]            = p00[r];
    red[w][(lb * 4 + r) * 32 + 16 + lm]       = p01[r];
    red[w][(16 + lb * 4 + r) * 32 + lm]       = p10[r];
    red[w][(16 + lb * 4 + r) * 32 + 16 + lm]  = p11[r];
  }
  __syncthreads();
  for (int k = tid; k < 1024; k += 256) {
    const float s = red[0][k] + red[1][k] + red[2][k] + red[3][k];
    atomicAdd(&ws[OFF_P + b * 1024 + k], s);
  }
  __syncthreads();
  // block reduce colsum[ch][i]
#pragma unroll
  for (int r = 0; r < 8; ++r) {
    const int ch = (r < 4) ? lb * 4 + r : 16 + lb * 4 + (r - 4);
    red[w][ch * 32 + lm]      = cs0[r];
    red[w][ch * 32 + 16 + lm] = cs1[r];
  }
  __syncthreads();
  for (int k = tid; k < 1024; k += 256) {
    const float s = red[0][k] + red[1][k] + red[2][k] + red[3][k];
    atomicAdd(&ws[OFF_CS + b * 1024 + k], s);
  }
}

// s = P + u.cs_i + v.cs_j + 8192*beta; A = softmax_j(s); also ca[j] and A-frags.
__global__ __launch_bounds__(1024) void softmax_kernel(float* __restrict__ ws) {
  const int j = threadIdx.x, i = threadIdx.y, b = blockIdx.x;
  __shared__ float A_lds[32][32];
  float s = ws[OFF_P + (b * 32 + i) * 32 + j] + 8192.0f * ws[OFF_BETA];
  for (int a = 0; a < 32; ++a) {
    s = fmaf(ws[OFF_U + a], ws[OFF_CS + (b * 32 + a) * 32 + i], s);
    s = fmaf(ws[OFF_V + a], ws[OFF_CS + (b * 32 + a) * 32 + j], s);
  }
  float mx = s;
#pragma unroll
  for (int off = 16; off > 0; off >>= 1) mx = fmaxf(mx, __shfl_xor(mx, off, 32));
  const float e = expf(s - mx);
  float sum = e;
#pragma unroll
  for (int off = 16; off > 0; off >>= 1) sum += __shfl_xor(sum, off, 32);
  A_lds[i][j] = e / sum;
  __syncthreads();
  if (i == 0) {
    float c = 0.f;
    for (int ii = 0; ii < 32; ++ii) c += A_lds[ii][j];
    ws[OFF_CA + b * 32 + j] = c;
  }
  const int tid = i * 32 + j;
  if (tid < 64) {
    const int lm = tid & 15, lb = tid >> 4;
    unsigned short* afr = (unsigned short*)(ws + OFF_AFRAG);
#pragma unroll
    for (int mt = 0; mt < 2; ++mt) {
#pragma unroll
      for (int r = 0; r < 8; ++r) {
        const int kk = (r < 4) ? lb * 4 + r : 16 + lb * 4 + (r - 4);
        // groupmix A-frag: A[m=j][k=i] = a[i][j]
        afr[((b * 2 + mt) * 64 + tid) * 8 + r] = f2bf(A_lds[kk][mt * 16 + lm]);
      }
    }
  }
}

// Pass 2: V = Wv*X (MFMA, transposed: D[pos][ch]); T = A^T x V (MFMA); out = x + gamma*T
__global__ __launch_bounds__(256) void pass2_kernel(
    const float* __restrict__ x, const float* __restrict__ bv,
    const float* __restrict__ gm, const float* __restrict__ ws,
    float* __restrict__ out) {
  const int tid = threadIdx.x;
  const int w = tid >> 6;
  const int l = tid & 63;
  const int lm = tid & 15;
  const int lb = (tid >> 4) & 3;
  const int b = blockIdx.y;
  const size_t xbase = (size_t)b * 32 * MSP;

  const bf16x8* WF = (const bf16x8*)(ws + OFF_WVFRAG);
  const bf16x8 wv0 = WF[0 * 64 + l];
  const bf16x8 wv1 = WF[1 * 64 + l];
  const bf16x8* AF = (const bf16x8*)(ws + OFF_AFRAG);
  const bf16x8 a0 = AF[(b * 2 + 0) * 64 + l];
  const bf16x8 a1 = AF[(b * 2 + 1) * 64 + l];
  const float gamma = gm[0];
  const float bv0 = bv[lm], bv1 = bv[16 + lm];

  float i00[4], i01[4], i10[4], i11[4];   // acc init = bv[ch] * ca[j]
#pragma unroll
  for (int r = 0; r < 4; ++r) {
    const float c0 = ws[OFF_CA + b * 32 + lb * 4 + r];
    const float c1 = ws[OFF_CA + b * 32 + 16 + lb * 4 + r];
    i00[r] = bv0 * c0; i01[r] = bv1 * c0;
    i10[r] = bv0 * c1; i11[r] = bv1 * c1;
  }

  const float* rowp[8];
#pragma unroll
  for (int r = 0; r < 8; ++r) {
    const int ch = (r < 4) ? lb * 4 + r : 16 + lb * 4 + (r - 4);
    rowp[r] = x + xbase + (size_t)ch * MSP + lm;
  }

  const int g0 = blockIdx.x * GPB + w * GPW;
#pragma unroll 2
  for (int t = 0; t < GPW; ++t) {
    const int p0 = (g0 + t) * 32;
    bf16x8 xh0, xh1;
#pragma unroll
    for (int r = 0; r < 8; ++r) {
      xh0[r] = (short)f2bf(rowp[r][p0]);
      xh1[r] = (short)f2bf(rowp[r][p0 + 16]);
    }
    // chmix transposed: D[m=pos][n=ch] = sum_cin X[cin][pos] * Wv[ch][cin]
    f32x4 v00 = {0,0,0,0}, v01 = {0,0,0,0}, v10 = {0,0,0,0}, v11 = {0,0,0,0};
    v00 = MFMA(xh0, wv0, v00); v01 = MFMA(xh0, wv1, v01);
    v10 = MFMA(xh1, wv0, v10); v11 = MFMA(xh1, wv1, v11);

    // V acc (row=pos=lb*4+reg within chunk, col=ch=lm) -> groupmix B-frag (k=i)
    bf16x8 vb0, vb1;
#pragma unroll
    for (int r = 0; r < 4; ++r) { vb0[r] = (short)f2bf(v00[r]); vb1[r] = (short)f2bf(v01[r]); }
#pragma unroll
    for (int r = 4; r < 8; ++r) { vb0[r] = (short)f2bf(v10[r - 4]); vb1[r] = (short)f2bf(v11[r - 4]); }

    // groupmix: D[m=j][n=ch] = sum_i a[i][j] * V[ch][i]  (+ bv*ca init)
    f32x4 t00 = {i00[0], i00[1], i00[2], i00[3]};
    f32x4 t01 = {i01[0], i01[1], i01[2], i01[3]};
    f32x4 t10 = {i10[0], i10[1], i10[2], i10[3]};
    f32x4 t11 = {i11[0], i11[1], i11[2], i11[3]};
    t00 = MFMA(a0, vb0, t00); t01 = MFMA(a0, vb1, t01);
    t10 = MFMA(a1, vb0, t10); t11 = MFMA(a1, vb1, t11);

    // epilogue: out[ch][p0 + j] = x + gamma * T   (j = mt*16 + lb*4 + reg, ch = ct*16 + lm)
#define EPI(TT, MT, CT)                                                           \
    {                                                                             \
      const size_t addr = xbase + (size_t)((CT) * 16 + lm) * MSP +                \
                          (size_t)(p0 + (MT) * 16 + lb * 4);                      \
      const float4 xr = *reinterpret_cast<const float4*>(x + addr);               \
      float4 o;                                                                   \
      o.x = fmaf(gamma, TT[0], xr.x); o.y = fmaf(gamma, TT[1], xr.y);             \
      o.z = fmaf(gamma, TT[2], xr.z); o.w = fmaf(gamma, TT[3], xr.w);             \
      *reinterpret_cast<float4*>(out + addr) = o;                                 \
    }
    EPI(t00, 0, 0); EPI(t01, 0, 1); EPI(t10, 1, 0); EPI(t11, 1, 1);
#undef EPI
  }
}

extern "C" void kernel_launch(void* const* d_in, const int* in_sizes, int n_in,
                              void* d_out, int out_size, void* d_ws, size_t ws_size,
                              hipStream_t stream) {
  const float* x  = (const float*)d_in[0];
  const float* Wq = (const float*)d_in[1];
  const float* bq = (const float*)d_in[2];
  const float* Wk = (const float*)d_in[3];
  const float* bk = (const float*)d_in[4];
  const float* Wv = (const float*)d_in[5];
  const float* bv = (const float*)d_in[6];
  const float* gm = (const float*)d_in[7];
  float* out = (float*)d_out;
  float* ws  = (float*)d_ws;

  prep_kernel<<<1, 1024, 0, stream>>>(Wq, bq, Wk, bk, Wv, ws);
  pass1_kernel<<<dim3(NBLK, BATCH), 256, 0, stream>>>(x, ws);
  softmax_kernel<<<BATCH, dim3(32, 32), 0, stream>>>(ws);
  pass2_kernel<<<dim3(NBLK, BATCH), 256, 0, stream>>>(x, bv, gm, ws, out);
}